// Round 3
// baseline (73.280 us; speedup 1.0000x reference)
//
#include <hip/hip_runtime.h>
#include <math.h>

// Problem constants
#define NS 64    // sentences
#define NW 64    // words per sentence
#define NE 300   // embedding dim
#define NH 50    // hidden
#define NO 5     // output classes
#define NPROD 64 // producer blocks (one per sentence)
#define TPB 192  // 3 waves per block

// d_ws layout (floats):
//   [0]          flag1 (int): producers-done counter
//   [1]          flag2 (int): scan-blocks-done counter
//   [64 ..]      Xg: 2*64*3*50 = 19200 floats (gate x-preactivations)
//   [64+19200..] gsum: 100 floats (per-direction mean hidden)

__device__ __forceinline__ float fast_tanh(float x) {
  x = fminf(15.f, fmaxf(-15.f, x));
  float e = __expf(2.f * x);
  return (e - 1.f) / (e + 1.f);
}
__device__ __forceinline__ float fast_sigmoid(float x) {
  return 1.f / (1.f + __expf(-x));
}

__global__ __launch_bounds__(TPB, 1) void k_all(
    const int* __restrict__ doc, const float* __restrict__ emb,
    const float* __restrict__ Wword, const float* __restrict__ bword,
    const float* __restrict__ w1, const float* __restrict__ b1,
    const float* __restrict__ w2, const float* __restrict__ b2,
    const float* __restrict__ w3, const float* __restrict__ b3,
    const float* __restrict__ Wfi, const float* __restrict__ bfi,
    const float* __restrict__ Wff, const float* __restrict__ bff,
    const float* __restrict__ Wfg, const float* __restrict__ bfg,
    const float* __restrict__ Wbi, const float* __restrict__ bbi,
    const float* __restrict__ Wbf, const float* __restrict__ bbf,
    const float* __restrict__ Wbg, const float* __restrict__ bbg,
    const float* __restrict__ Wout, const float* __restrict__ bout,
    float* __restrict__ ws, float* __restrict__ out)
{
  int*   flag1 = (int*)ws;
  int*   flag2 = (int*)ws + 1;
  float* XgG   = ws + 64;
  float* gsumG = ws + 64 + 2 * NS * 3 * NH;

  // Scan-side LDS
  __shared__ float Xlds[NS * 3 * NH];   // 38400 B, one direction's X
  __shared__ float h_sh[56];            // padded so float4 reads cover 52
  __shared__ float gate_sh[3][64];
  __shared__ int   last_sh;
  // Producer-side LDS
  __shared__ int   idxs[NW];
  __shared__ float sv[5][304];          // 0: word-sum; 1..4: rows 0,1,62,63
  __shared__ float dots[5][NH];
  __shared__ float reps_s[NH];

  const int tid = threadIdx.x;
  const int b   = blockIdx.x;

  if (b < NPROD) {
    // =============================== producer ===============================
    const int s = b;
    if (tid < NW) idxs[tid] = doc[s * NW + tid];
    __syncthreads();

    // Phase B: column sums of the 64 gathered embedding rows (coalesced in e).
    for (int e = tid; e < NE; e += TPB) {
      float acc = 0.f;
#pragma unroll 16
      for (int w = 0; w < NW; ++w)
        acc += emb[(size_t)idxs[w] * NE + e];
      sv[0][e] = acc;
      sv[1][e] = emb[(size_t)idxs[0]  * NE + e];
      sv[2][e] = emb[(size_t)idxs[1]  * NE + e];
      sv[3][e] = emb[(size_t)idxs[62] * NE + e];
      sv[4][e] = emb[(size_t)idxs[63] * NE + e];
    }
    __syncthreads();

    // Phase C: 5 families x 50 outputs, 300-dots against W_word rows.
    for (int task = tid; task < 5 * NH; task += TPB) {
      const int fam = task / NH, i = task % NH;
      const float4* v4 = (const float4*)&sv[fam][0];
      const float4* w4 = (const float4*)(Wword + (size_t)i * NE);
      float a0 = 0.f, a1 = 0.f;
#pragma unroll
      for (int c = 0; c < NE / 4; ++c) {
        const float4 v = v4[c], w = w4[c];
        a0 += v.x * w.x + v.y * w.y;
        a1 += v.z * w.z + v.w * w.w;
      }
      dots[fam][i] = a0 + a1;
    }
    __syncthreads();

    // Phase D: conv means + tanh + average -> reps_s
    if (tid < NH) {
      const int o = tid;
      float m1 = 0.f, m2 = 0.f, m3 = 0.f;
      for (int i = 0; i < NH; ++i) {
        const float bw    = bword[i];
        const float total = dots[0][i] + 64.f * bw;
        const float e0  = dots[1][i] + bw;
        const float e1  = dots[2][i] + bw;
        const float e62 = dots[3][i] + bw;
        const float e63 = dots[4][i] + bw;
        m1 += w1[o * NH + i] * total;
        m2 += w2[(o * NH + i) * 2 + 0] * (total - e63)
            + w2[(o * NH + i) * 2 + 1] * (total - e0);
        m3 += w3[(o * NH + i) * 3 + 0] * (total - e62 - e63)
            + w3[(o * NH + i) * 3 + 1] * (total - e0 - e63)
            + w3[(o * NH + i) * 3 + 2] * (total - e0 - e1);
      }
      m1 = b1[o] + m1 * (1.f / 64.f);
      m2 = b2[o] + m2 * (1.f / 63.f);
      m3 = b3[o] + m3 * (1.f / 62.f);
      reps_s[o] = (fast_tanh(m1) + fast_tanh(m2) + fast_tanh(m3)) * (1.f / 3.f);
    }
    __syncthreads();

    // Phase E: x-part gate preactivations for both directions.
    for (int task = tid; task < 6 * NH; task += TPB) {
      const int dg = task / NH, j = task % NH;
      const float* Wp; const float* bp;
      switch (dg) {
        case 0: Wp = Wfi; bp = bfi; break;
        case 1: Wp = Wff; bp = bff; break;
        case 2: Wp = Wfg; bp = bfg; break;
        case 3: Wp = Wbi; bp = bbi; break;
        case 4: Wp = Wbf; bp = bbf; break;
        default: Wp = Wbg; bp = bbg; break;
      }
      float acc = bp[j];
      for (int k = 0; k < NH; ++k) acc += Wp[j * 100 + k] * reps_s[k];
      const int dir = dg / 3, gate = dg % 3;
      XgG[((dir * NS + s) * 3 + gate) * NH + j] = acc;
    }
    __syncthreads();   // all waves' Xg writes retired to L2 (vmcnt drain)

    if (tid == 0) {
      __threadfence(); // agent-scope: write back L2 so other XCDs see Xg
      __hip_atomic_fetch_add(flag1, 1, __ATOMIC_RELEASE, __HIP_MEMORY_SCOPE_AGENT);
    }
    return;
  }

  // ================================ scan ===================================
  const int d    = b - NPROD;           // direction 0=fwd, 1=bwd
  const int wid  = tid >> 6, lane = tid & 63;
  const int g    = wid;                 // gate: 0=i, 1=f, 2=g
  const int j    = (lane < NH) ? lane : 0;

  const float* Wp = (d == 0) ? ((g == 0) ? Wfi : (g == 1) ? Wff : Wfg)
                             : ((g == 0) ? Wbi : (g == 1) ? Wbf : Wbg);

  // 50 h-weights per lane (+2 zero pad for the float4 dot) — loaded while
  // producers are still running (overlapped with the spin-wait).
  float wk[52];
#pragma unroll
  for (int k = 0; k < NH; ++k) wk[k] = Wp[j * 100 + 50 + k];
  wk[50] = 0.f; wk[51] = 0.f;
  if (tid < 56) h_sh[tid] = 0.f;

  if (tid == 0) {
    while (__hip_atomic_load(flag1, __ATOMIC_ACQUIRE, __HIP_MEMORY_SCOPE_AGENT) < NPROD)
      __builtin_amdgcn_s_sleep(2);
    __threadfence();   // invalidate stale lines (prev replay) before Xg reads
  }
  __syncthreads();

  // Stage this direction's X into LDS: 9600 floats, coalesced float4.
  {
    const float4* src = (const float4*)(XgG + d * NS * 3 * NH);
    float4* dst = (float4*)Xlds;
    for (int i = tid; i < NS * 3 * NH / 4; i += TPB) dst[i] = src[i];
  }
  __syncthreads();

  // 64 sequential steps. Loop body is LDS/VALU only — no VMEM, so barriers
  // don't drain vmcnt.
  float hj = 0.f, hs = 0.f;
  for (int n = 0; n < NS; ++n) {
    const int t = d ? (NS - 1 - n) : n;
    float a = Xlds[(t * 3 + g) * NH + j];

    const float4* h4 = (const float4*)h_sh;  // uniform-address broadcast reads
    float a0 = 0.f, a1 = 0.f;
#pragma unroll
    for (int c = 0; c < 13; ++c) {
      const float4 hv = h4[c];
      a0 += wk[4 * c + 0] * hv.x;
      a1 += wk[4 * c + 1] * hv.y;
      a0 += wk[4 * c + 2] * hv.z;
      a1 += wk[4 * c + 3] * hv.w;
    }
    a += a0 + a1;

    const float act = (g == 2) ? fast_tanh(a) : fast_sigmoid(a);
    if (lane < NH) gate_sh[g][lane] = act;
    __syncthreads();                       // gates ready; h_sh reads done

    const float iv = gate_sh[0][j];
    const float fv = gate_sh[1][j];
    const float gv = gate_sh[2][j];
    hj = fast_tanh(iv * gv + fv * hj);     // redundant across the 3 waves
    hs += hj;
    if (g == 0 && lane < NH) h_sh[lane] = hj;
    __syncthreads();                       // new h visible
  }

  if (g == 0 && lane < NH) gsumG[d * NH + lane] = hs * (1.f / 64.f);
  __syncthreads();   // gsum writes retired

  if (tid == 0) {
    __threadfence();
    const int old = __hip_atomic_fetch_add(flag2, 1, __ATOMIC_ACQ_REL,
                                           __HIP_MEMORY_SCOPE_AGENT);
    if (old == 1) __threadfence();  // acquire other direction's gsum
    last_sh = (old == 1);
  }
  __syncthreads();
  if (!last_sh) return;

  // Epilogue (last scan block, wave 0): logits + softmax
  if (wid == 0) {
    float lg = 0.f;
    if (lane < NO) {
      float acc = bout[lane];
      for (int k = 0; k < 2 * NH; ++k) acc += Wout[lane * 2 * NH + k] * gsumG[k];
      lg = acc;
    }
    const float l0 = __shfl(lg, 0), l1 = __shfl(lg, 1), l2 = __shfl(lg, 2),
                l3 = __shfl(lg, 3), l4 = __shfl(lg, 4);
    if (lane == 0) {
      const float m = fmaxf(fmaxf(fmaxf(l0, l1), fmaxf(l2, l3)), l4);
      const float e0 = __expf(l0 - m), e1 = __expf(l1 - m), e2 = __expf(l2 - m),
                  e3 = __expf(l3 - m), e4 = __expf(l4 - m);
      const float se = e0 + e1 + e2 + e3 + e4;
      out[0] = e0 / se; out[1] = e1 / se; out[2] = e2 / se;
      out[3] = e3 / se; out[4] = e4 / se;
    }
  }
}

extern "C" void kernel_launch(void* const* d_in, const int* in_sizes, int n_in,
                              void* d_out, int out_size, void* d_ws, size_t ws_size,
                              hipStream_t stream) {
  const int*   doc   = (const int*)  d_in[0];
  const float* emb   = (const float*)d_in[1];
  const float* Wword = (const float*)d_in[2];
  const float* bword = (const float*)d_in[3];
  const float* w1    = (const float*)d_in[4];
  const float* b1    = (const float*)d_in[5];
  const float* w2    = (const float*)d_in[6];
  const float* b2    = (const float*)d_in[7];
  const float* w3    = (const float*)d_in[8];
  const float* b3    = (const float*)d_in[9];
  const float* Wfi   = (const float*)d_in[10];
  const float* bfi   = (const float*)d_in[11];
  const float* Wff   = (const float*)d_in[12];
  const float* bff   = (const float*)d_in[13];
  const float* Wfg   = (const float*)d_in[14];
  const float* bfg   = (const float*)d_in[15];
  const float* Wbi   = (const float*)d_in[16];
  const float* bbi   = (const float*)d_in[17];
  const float* Wbf   = (const float*)d_in[18];
  const float* bbf   = (const float*)d_in[19];
  const float* Wbg   = (const float*)d_in[20];
  const float* bbg   = (const float*)d_in[21];
  const float* Wout  = (const float*)d_in[22];
  const float* bout  = (const float*)d_in[23];

  // zero the two sync flags (graph-capturable async memset)
  hipMemsetAsync(d_ws, 0, 8, stream);

  k_all<<<dim3(NPROD + 2), dim3(TPB), 0, stream>>>(
      doc, emb, Wword, bword, w1, b1, w2, b2, w3, b3,
      Wfi, bfi, Wff, bff, Wfg, bfg, Wbi, bbi, Wbf, bbf, Wbg, bbg,
      Wout, bout, (float*)d_ws, (float*)d_out);
}